// Round 1
// baseline (119.058 us; speedup 1.0000x reference)
//
#include <hip/hip_runtime.h>
#include <stdint.h>

#define SEQ 512
#define BATCH 8
#define HID 1024

typedef __attribute__((ext_vector_type(8))) __bf16 bf16x8;
typedef __attribute__((ext_vector_type(4))) float f32x4;

__device__ __forceinline__ unsigned short f2bf(float f) {
    unsigned int u = __float_as_uint(f);
    unsigned int r = 0x7fffu + ((u >> 16) & 1u);
    return (unsigned short)((u + r) >> 16);
}

// ---- 1. cast sequence_output (fp32) -> bf16, flat ----
__global__ void k_cast(const float4* __restrict__ in, ushort4* __restrict__ out, int n4) {
    int i = blockIdx.x * blockDim.x + threadIdx.x;
    if (i >= n4) return;
    float4 v = in[i];
    ushort4 o;
    o.x = f2bf(v.x); o.y = f2bf(v.y); o.z = f2bf(v.z); o.w = f2bf(v.w);
    out[i] = o;
}

// ---- 2. Bt[n][k] = bf16( n<1024 ? W1[k][n] : W1[1024+k][n-1024] ), LDS-tiled transpose ----
__global__ __launch_bounds__(256) void k_bt(const float* __restrict__ W1, ushort* __restrict__ Bt) {
    __shared__ float tile[32][33];
    int tx = threadIdx.x & 31;
    int ty = threadIdx.x >> 5;
    int nb = blockIdx.x * 32, kb = blockIdx.y * 32;
    int n = nb + tx;
    int rb = (n < 1024) ? 0 : 1024;
    int nc = n - rb;
#pragma unroll
    for (int i = 0; i < 4; ++i) {
        int k = kb + ty + i * 8;
        tile[ty + i * 8][tx] = W1[(size_t)(rb + k) * 1024 + nc];
    }
    __syncthreads();
#pragma unroll
    for (int i = 0; i < 4; ++i) {
        int n2 = nb + ty + i * 8;
        Bt[(size_t)n2 * 1024 + kb + tx] = f2bf(tile[tx][ty + i * 8]);
    }
}

// ---- 3. Rw[w][j] = b1[j] + sum_c wemb[w][c] * W1[2048+c][j]  (15 x 1024) ----
__global__ void k_width(const float* __restrict__ wemb, const float* __restrict__ W1,
                        const float* __restrict__ b1, float* __restrict__ Rw) {
    int idx = blockIdx.x * blockDim.x + threadIdx.x;
    if (idx >= 15 * 1024) return;
    int w = idx >> 10, j = idx & 1023;
    float acc = b1[j];
#pragma unroll
    for (int c = 0; c < 64; ++c)
        acc = fmaf(wemb[w * 64 + c], W1[(size_t)(2048 + c) * 1024 + j], acc);
    Rw[idx] = acc;
}

// ---- 4. bf16 MFMA GEMM: C[4096][2048] = A[4096][1024] * Bt[2048][1024]^T ----
// m97 structure: 128x128 tile, 4 waves (2x2 of 64x64), BK=32, global_load_lds w=16
__global__ __launch_bounds__(256) void k_gemm(const ushort* __restrict__ A,
                                              const ushort* __restrict__ Bt,
                                              float* __restrict__ C) {
    __shared__ ushort Al[128 * 32];
    __shared__ ushort Bl[128 * 32];
    const int tid = threadIdx.x;
    const int wid = tid >> 6;
    const int lane = tid & 63;
    const int m0 = blockIdx.y * 128;
    const int n0 = blockIdx.x * 128;
    const int wm = (wid >> 1) * 64;
    const int wn = (wid & 1) * 64;
    const int srow = lane >> 2;        // staging: row within 16-row chunk
    const int scol = (lane & 3) * 8;   // staging: element col
    const int fr = lane & 15;          // fragment row (A) / col (B)
    const int fk = (lane >> 4) * 8;    // fragment k offset

    f32x4 acc[4][4] = {};

    for (int k0 = 0; k0 < 1024; k0 += 32) {
#pragma unroll
        for (int r = 0; r < 2; ++r) {
            int c = wid + 4 * r;  // chunk 0..7 (16 rows each)
            const ushort* sa = A  + (size_t)(m0 + c * 16 + srow) * 1024 + k0 + scol;
            const ushort* sb = Bt + (size_t)(n0 + c * 16 + srow) * 1024 + k0 + scol;
            __builtin_amdgcn_global_load_lds((const __attribute__((address_space(1))) void*)sa,
                                             (__attribute__((address_space(3))) void*)(Al + c * 16 * 32),
                                             16, 0, 0);
            __builtin_amdgcn_global_load_lds((const __attribute__((address_space(1))) void*)sb,
                                             (__attribute__((address_space(3))) void*)(Bl + c * 16 * 32),
                                             16, 0, 0);
        }
        __syncthreads();  // compiler drains vmcnt before barrier
        bf16x8 af[4], bg[4];
#pragma unroll
        for (int i = 0; i < 4; ++i) {
            af[i] = *(const bf16x8*)(Al + ((wm + i * 16 + fr) * 32 + fk));
            bg[i] = *(const bf16x8*)(Bl + ((wn + i * 16 + fr) * 32 + fk));
        }
#pragma unroll
        for (int i = 0; i < 4; ++i)
#pragma unroll
            for (int j = 0; j < 4; ++j)
                acc[i][j] = __builtin_amdgcn_mfma_f32_16x16x32_bf16(af[i], bg[j], acc[i][j], 0, 0, 0);
        __syncthreads();
    }

    const int cr = (lane >> 4) * 4;
    const int cc = lane & 15;
#pragma unroll
    for (int i = 0; i < 4; ++i)
#pragma unroll
        for (int j = 0; j < 4; ++j) {
            float* Cp = C + (size_t)(m0 + wm + i * 16 + cr) * 2048 + (n0 + wn + j * 16 + cc);
#pragma unroll
            for (int r = 0; r < 4; ++r)
                Cp[(size_t)r * 2048] = acc[i][j][r];
        }
}

// ---- 5. span pass: logits[b,n,:] = relu(P[b,s]+Q[b,e]+R[e-s]) @ W2 + b2 ----
__global__ __launch_bounds__(256) void k_span(const float* __restrict__ PQ,
                                              const float* __restrict__ Rw,
                                              const float* __restrict__ W2,
                                              const float* __restrict__ b2,
                                              const int* __restrict__ starts,
                                              const int* __restrict__ ends,
                                              float* __restrict__ out,
                                              int nspans, int totalM) {
    __shared__ float w2s[3 * 1024];  // transposed: w2s[l*1024 + j]
    int tid = threadIdx.x;
    for (int idx = tid; idx < 3 * 1024; idx += 256) {
        int l = idx >> 10, j = idx & 1023;
        w2s[idx] = W2[j * 3 + l];
    }
    __syncthreads();
    int wid = tid >> 6, lane = tid & 63;
    int m = blockIdx.x * 4 + wid;
    if (m >= totalM) return;
    int b = m / nspans;
    int n = m - b * nspans;
    int s = starts[n], e = ends[n];
    const float* P = PQ + (size_t)(b * SEQ + s) * 2048;
    const float* Q = PQ + (size_t)(b * SEQ + e) * 2048 + 1024;
    const float* R = Rw + (size_t)(e - s) * 1024;
    float a0 = 0.f, a1 = 0.f, a2 = 0.f;
#pragma unroll
    for (int it = 0; it < 16; ++it) {
        int j = it * 64 + lane;
        float h = P[j] + Q[j] + R[j];
        h = fmaxf(h, 0.f);
        a0 = fmaf(h, w2s[j], a0);
        a1 = fmaf(h, w2s[1024 + j], a1);
        a2 = fmaf(h, w2s[2048 + j], a2);
    }
#pragma unroll
    for (int off = 32; off > 0; off >>= 1) {
        a0 += __shfl_xor(a0, off);
        a1 += __shfl_xor(a1, off);
        a2 += __shfl_xor(a2, off);
    }
    if (lane == 0) {
        float* o = out + (size_t)m * 3;
        o[0] = a0 + b2[0];
        o[1] = a1 + b2[1];
        o[2] = a2 + b2[2];
    }
}

extern "C" void kernel_launch(void* const* d_in, const int* in_sizes, int n_in,
                              void* d_out, int out_size, void* d_ws, size_t ws_size,
                              hipStream_t stream) {
    const float* seq    = (const float*)d_in[0];
    const float* wemb   = (const float*)d_in[1];
    const float* W1     = (const float*)d_in[2];
    const float* b1     = (const float*)d_in[3];
    const float* W2     = (const float*)d_in[4];
    const float* b2     = (const float*)d_in[5];
    const int*   starts = (const int*)d_in[6];
    const int*   ends   = (const int*)d_in[7];
    float* out = (float*)d_out;
    int nspans = in_sizes[6];
    int totalM = BATCH * nspans;

    char* ws = (char*)d_ws;
    ushort* seqb = (ushort*)ws;                  // 8 MiB  (4096x1024 bf16)
    ushort* Bt   = (ushort*)(ws + (8u << 20));   // 4 MiB  (2048x1024 bf16)
    float*  PQ   = (float*)(ws + (12u << 20));   // 32 MiB (4096x2048 f32)
    float*  Rw   = (float*)(ws + (44u << 20));   // 60 KiB (15x1024 f32)

    int n4 = (BATCH * SEQ * HID) / 4;
    hipLaunchKernelGGL(k_cast, dim3((n4 + 255) / 256), dim3(256), 0, stream,
                       (const float4*)seq, (ushort4*)seqb, n4);
    hipLaunchKernelGGL(k_bt, dim3(64, 32), dim3(256), 0, stream, W1, Bt);
    hipLaunchKernelGGL(k_width, dim3(60), dim3(256), 0, stream, wemb, W1, b1, Rw);
    hipLaunchKernelGGL(k_gemm, dim3(16, 32), dim3(256), 0, stream, seqb, Bt, PQ);
    int blocks = (totalM + 3) / 4;
    hipLaunchKernelGGL(k_span, dim3(blocks), dim3(256), 0, stream,
                       PQ, Rw, W2, b2, starts, ends, out, nspans, totalM);
}

// Round 2
// 66.967 us; speedup vs baseline: 1.7779x; 1.7779x over previous
//
#include <hip/hip_runtime.h>
#include <stdint.h>

#define SEQ 512
#define BATCH 8
#define HID 1024

typedef __attribute__((ext_vector_type(8))) __bf16 bf16x8;
typedef __attribute__((ext_vector_type(4))) float f32x4;

__device__ __forceinline__ unsigned short f2bf(float f) {
    unsigned int u = __float_as_uint(f);
    unsigned int r = 0x7fffu + ((u >> 16) & 1u);
    return (unsigned short)((u + r) >> 16);
}

__device__ __forceinline__ void unpack8(uint4 v, float* f) {
    f[0] = __uint_as_float(v.x << 16);
    f[1] = __uint_as_float(v.x & 0xffff0000u);
    f[2] = __uint_as_float(v.y << 16);
    f[3] = __uint_as_float(v.y & 0xffff0000u);
    f[4] = __uint_as_float(v.z << 16);
    f[5] = __uint_as_float(v.z & 0xffff0000u);
    f[6] = __uint_as_float(v.w << 16);
    f[7] = __uint_as_float(v.w & 0xffff0000u);
}

// ---- 1. cast sequence_output (fp32) -> bf16, flat ----
__global__ void k_cast(const float4* __restrict__ in, ushort4* __restrict__ out, int n4) {
    int i = blockIdx.x * blockDim.x + threadIdx.x;
    if (i >= n4) return;
    float4 v = in[i];
    ushort4 o;
    o.x = f2bf(v.x); o.y = f2bf(v.y); o.z = f2bf(v.z); o.w = f2bf(v.w);
    out[i] = o;
}

// ---- 2. Bt[n][k] = bf16( n<1024 ? W1[k][n] : W1[1024+k][n-1024] ) ----
__global__ __launch_bounds__(256) void k_bt(const float* __restrict__ W1, ushort* __restrict__ Bt) {
    __shared__ float tile[32][33];
    int tx = threadIdx.x & 31;
    int ty = threadIdx.x >> 5;
    int nb = blockIdx.x * 32, kb = blockIdx.y * 32;
    int n = nb + tx;
    int rb = (n < 1024) ? 0 : 1024;
    int nc = n - rb;
#pragma unroll
    for (int i = 0; i < 4; ++i) {
        int k = kb + ty + i * 8;
        tile[ty + i * 8][tx] = W1[(size_t)(rb + k) * 1024 + nc];
    }
    __syncthreads();
#pragma unroll
    for (int i = 0; i < 4; ++i) {
        int n2 = nb + ty + i * 8;
        Bt[(size_t)n2 * 1024 + kb + tx] = f2bf(tile[tx][ty + i * 8]);
    }
}

// ---- 3. Rbf[w][j] = bf16( b1[j] + sum_c wemb[w][c] * W1[2048+c][j] ) ----
__global__ void k_width(const float* __restrict__ wemb, const float* __restrict__ W1,
                        const float* __restrict__ b1, ushort* __restrict__ Rbf) {
    int idx = blockIdx.x * blockDim.x + threadIdx.x;
    if (idx >= 15 * 1024) return;
    int w = idx >> 10, j = idx & 1023;
    float acc = b1[j];
#pragma unroll
    for (int c = 0; c < 64; ++c)
        acc = fmaf(wemb[w * 64 + c], W1[(size_t)(2048 + c) * 1024 + j], acc);
    Rbf[idx] = f2bf(acc);
}

// ---- 4. bf16 MFMA GEMM -> bf16 P (cols 0..1023) / Q (cols 1024..2047) ----
__global__ __launch_bounds__(256) void k_gemm(const ushort* __restrict__ A,
                                              const ushort* __restrict__ Bt,
                                              ushort* __restrict__ P,
                                              ushort* __restrict__ Q) {
    __shared__ ushort Al[128 * 32];
    __shared__ ushort Bl[128 * 32];
    const int tid = threadIdx.x;
    const int wid = tid >> 6;
    const int lane = tid & 63;
    const int m0 = blockIdx.y * 128;
    const int n0 = blockIdx.x * 128;
    const int wm = (wid >> 1) * 64;
    const int wn = (wid & 1) * 64;
    const int srow = lane >> 2;
    const int scol = (lane & 3) * 8;
    const int fr = lane & 15;
    const int fk = (lane >> 4) * 8;

    f32x4 acc[4][4] = {};

    for (int k0 = 0; k0 < 1024; k0 += 32) {
#pragma unroll
        for (int r = 0; r < 2; ++r) {
            int c = wid + 4 * r;
            const ushort* sa = A  + (size_t)(m0 + c * 16 + srow) * 1024 + k0 + scol;
            const ushort* sb = Bt + (size_t)(n0 + c * 16 + srow) * 1024 + k0 + scol;
            __builtin_amdgcn_global_load_lds((const __attribute__((address_space(1))) void*)sa,
                                             (__attribute__((address_space(3))) void*)(Al + c * 16 * 32),
                                             16, 0, 0);
            __builtin_amdgcn_global_load_lds((const __attribute__((address_space(1))) void*)sb,
                                             (__attribute__((address_space(3))) void*)(Bl + c * 16 * 32),
                                             16, 0, 0);
        }
        __syncthreads();
        bf16x8 af[4], bg[4];
#pragma unroll
        for (int i = 0; i < 4; ++i) {
            af[i] = *(const bf16x8*)(Al + ((wm + i * 16 + fr) * 32 + fk));
            bg[i] = *(const bf16x8*)(Bl + ((wn + i * 16 + fr) * 32 + fk));
        }
#pragma unroll
        for (int i = 0; i < 4; ++i)
#pragma unroll
            for (int j = 0; j < 4; ++j)
                acc[i][j] = __builtin_amdgcn_mfma_f32_16x16x32_bf16(af[i], bg[j], acc[i][j], 0, 0, 0);
        __syncthreads();
    }

    ushort* Cb = (n0 < 1024) ? P : Q;
    const int nc0 = n0 & 1023;
    const int cr = (lane >> 4) * 4;
    const int cc = lane & 15;
#pragma unroll
    for (int i = 0; i < 4; ++i)
#pragma unroll
        for (int j = 0; j < 4; ++j) {
            ushort* Cp = Cb + (size_t)(m0 + wm + i * 16 + cr) * 1024 + (nc0 + wn + j * 16 + cc);
#pragma unroll
            for (int r = 0; r < 4; ++r)
                Cp[(size_t)r * 1024] = f2bf(acc[i][j][r]);
        }
}

// ---- 5. span pass with reuse tiling ----
// block = (batch, 16-start window); wave = one start; 30 Q rows + 15 R rows in LDS.
__global__ __launch_bounds__(1024) void k_span2(const ushort* __restrict__ Pmat,
                                                const ushort* __restrict__ Qmat,
                                                const ushort* __restrict__ Rbf,
                                                const float* __restrict__ W2,
                                                const float* __restrict__ b2,
                                                float* __restrict__ out, int nspans) {
    __shared__ ushort Qs[30 * 1024];  // rows s0 .. s0+29 (clamped), bf16
    __shared__ ushort Rs[15 * 1024];
    const int tid = threadIdx.x;
    const int wid = tid >> 6, lane = tid & 63;
    const int b = blockIdx.x >> 5;
    const int s0 = (blockIdx.x & 31) << 4;

    // fill Q: 60 chunks of 1 KiB (64 lanes x 16B)
#pragma unroll
    for (int i = 0; i < 4; ++i) {
        int c = wid + (i << 4);
        if (c < 60) {
            int g = (c << 9) + lane * 8;
            int row = s0 + (g >> 10);
            if (row > SEQ - 1) row = SEQ - 1;
            const ushort* src = Qmat + (((size_t)(b << 9) + row) << 10) + (g & 1023);
            __builtin_amdgcn_global_load_lds((const __attribute__((address_space(1))) void*)src,
                                             (__attribute__((address_space(3))) void*)(Qs + (c << 9)),
                                             16, 0, 0);
        }
    }
    // fill R: 30 chunks
#pragma unroll
    for (int i = 0; i < 2; ++i) {
        int c = wid + (i << 4);
        if (c < 30) {
            int g = (c << 9) + lane * 8;
            __builtin_amdgcn_global_load_lds((const __attribute__((address_space(1))) void*)(Rbf + g),
                                             (__attribute__((address_space(3))) void*)(Rs + (c << 9)),
                                             16, 0, 0);
        }
    }

    // hoisted per-lane constants: j = lane*8 + it*512 + u
    float w2r[3][2][8];
#pragma unroll
    for (int it = 0; it < 2; ++it)
#pragma unroll
        for (int u = 0; u < 8; ++u) {
            int j = lane * 8 + it * 512 + u;
            w2r[0][it][u] = W2[j * 3 + 0];
            w2r[1][it][u] = W2[j * 3 + 1];
            w2r[2][it][u] = W2[j * 3 + 2];
        }
    const float bb0 = b2[0], bb1 = b2[1], bb2 = b2[2];

    // P row in f32 regs
    const int s = s0 + wid;
    float pf[16];
    {
        const uint4* pr = (const uint4*)(Pmat + (((size_t)(b << 9) + s) << 10) + lane * 8);
        unpack8(pr[0], pf);
        unpack8(pr[64], pf + 8);  // +1024B = +64 uint4
    }

    __syncthreads();  // Qs/Rs ready (vmcnt drained by barrier)

    const int rrem = SEQ - s;
    const int nsp = (rrem < 15) ? rrem : 15;
    const int off = (rrem >= 15) ? 15 * s : (7575 - (rrem * (rrem + 1)) / 2);
    float* op = out + ((size_t)b * nspans + off) * 3;

    for (int w = 0; w < nsp; ++w) {
        const int erow = wid + w;
        float a0 = 0.f, a1 = 0.f, a2 = 0.f;
#pragma unroll
        for (int it = 0; it < 2; ++it) {
            uint4 qv = *(const uint4*)((const char*)Qs + erow * 2048 + it * 1024 + lane * 16);
            uint4 rv = *(const uint4*)((const char*)Rs + w * 2048 + it * 1024 + lane * 16);
            float qf[8], rf[8];
            unpack8(qv, qf);
            unpack8(rv, rf);
#pragma unroll
            for (int u = 0; u < 8; ++u) {
                float h = pf[it * 8 + u] + qf[u] + rf[u];
                h = fmaxf(h, 0.f);
                a0 = fmaf(h, w2r[0][it][u], a0);
                a1 = fmaf(h, w2r[1][it][u], a1);
                a2 = fmaf(h, w2r[2][it][u], a2);
            }
        }
#pragma unroll
        for (int o = 32; o; o >>= 1) {
            a0 += __shfl_xor(a0, o);
            a1 += __shfl_xor(a1, o);
            a2 += __shfl_xor(a2, o);
        }
        if (lane == 0) {
            op[w * 3 + 0] = a0 + bb0;
            op[w * 3 + 1] = a1 + bb1;
            op[w * 3 + 2] = a2 + bb2;
        }
    }
}

extern "C" void kernel_launch(void* const* d_in, const int* in_sizes, int n_in,
                              void* d_out, int out_size, void* d_ws, size_t ws_size,
                              hipStream_t stream) {
    const float* seq    = (const float*)d_in[0];
    const float* wemb   = (const float*)d_in[1];
    const float* W1     = (const float*)d_in[2];
    const float* b1     = (const float*)d_in[3];
    const float* W2     = (const float*)d_in[4];
    const float* b2     = (const float*)d_in[5];
    float* out = (float*)d_out;
    int nspans = in_sizes[6];

    char* ws = (char*)d_ws;
    ushort* seqb = (ushort*)ws;                  // 8 MiB  (4096x1024 bf16)
    ushort* Bt   = (ushort*)(ws + (8u << 20));   // 4 MiB  (2048x1024 bf16)
    ushort* Pmat = (ushort*)(ws + (12u << 20));  // 8 MiB  (4096x1024 bf16)
    ushort* Qmat = (ushort*)(ws + (20u << 20));  // 8 MiB  (4096x1024 bf16)
    ushort* Rbf  = (ushort*)(ws + (28u << 20));  // 30 KiB (15x1024 bf16)

    int n4 = (BATCH * SEQ * HID) / 4;
    hipLaunchKernelGGL(k_cast, dim3((n4 + 255) / 256), dim3(256), 0, stream,
                       (const float4*)seq, (ushort4*)seqb, n4);
    hipLaunchKernelGGL(k_bt, dim3(64, 32), dim3(256), 0, stream, W1, Bt);
    hipLaunchKernelGGL(k_width, dim3(60), dim3(256), 0, stream, wemb, W1, b1, Rbf);
    hipLaunchKernelGGL(k_gemm, dim3(16, 32), dim3(256), 0, stream, seqb, Bt, Pmat, Qmat);
    hipLaunchKernelGGL(k_span2, dim3(BATCH * (SEQ / 16)), dim3(1024), 0, stream,
                       Pmat, Qmat, Rbf, W2, b2, out, nspans);
}

// Round 4
// 62.690 us; speedup vs baseline: 1.8992x; 1.0682x over previous
//
#include <hip/hip_runtime.h>
#include <stdint.h>

#define SEQ 512
#define BATCH 8
#define HID 1024

typedef __attribute__((ext_vector_type(8))) __bf16 bf16x8;
typedef __attribute__((ext_vector_type(4))) float f32x4;

__device__ __forceinline__ unsigned short f2bf(float f) {
    unsigned int u = __float_as_uint(f);
    unsigned int r = 0x7fffu + ((u >> 16) & 1u);
    return (unsigned short)((u + r) >> 16);
}

__device__ __forceinline__ void unpack8(uint4 v, float* f) {
    f[0] = __uint_as_float(v.x << 16);
    f[1] = __uint_as_float(v.x & 0xffff0000u);
    f[2] = __uint_as_float(v.y << 16);
    f[3] = __uint_as_float(v.y & 0xffff0000u);
    f[4] = __uint_as_float(v.z << 16);
    f[5] = __uint_as_float(v.z & 0xffff0000u);
    f[6] = __uint_as_float(v.w << 16);
    f[7] = __uint_as_float(v.w & 0xffff0000u);
}

// ---- 1. merged prep ----
// blocks [0,4096): cast seq->bf16 (1,048,576 float4s)
// blocks [4096,6144): transpose W1[:2048] -> Bt bf16
// blocks [6144,6204): width table Rbf
__global__ __launch_bounds__(256) void k_prep(const float* __restrict__ seq,
                                              const float* __restrict__ wemb,
                                              const float* __restrict__ W1,
                                              const float* __restrict__ b1,
                                              ushort* __restrict__ seqb,
                                              ushort* __restrict__ Bt,
                                              ushort* __restrict__ Rbf) {
    __shared__ float tile[32][33];
    const int bid = blockIdx.x;
    const int tid = threadIdx.x;
    if (bid < 4096) {
        int i = bid * 256 + tid;  // < 1048576 = n4
        float4 v = ((const float4*)seq)[i];
        ushort4 o;
        o.x = f2bf(v.x); o.y = f2bf(v.y); o.z = f2bf(v.z); o.w = f2bf(v.w);
        ((ushort4*)seqb)[i] = o;
    } else if (bid < 6144) {
        int idx = bid - 4096;
        int nb = (idx & 63) * 32, kb = (idx >> 6) * 32;
        int tx = tid & 31, ty = tid >> 5;
        int n = nb + tx;
        int rb = (n < 1024) ? 0 : 1024;
        int nc = n - rb;
#pragma unroll
        for (int i = 0; i < 4; ++i) {
            int k = kb + ty + i * 8;
            tile[ty + i * 8][tx] = W1[(size_t)(rb + k) * 1024 + nc];
        }
        __syncthreads();
#pragma unroll
        for (int i = 0; i < 4; ++i) {
            int n2 = nb + ty + i * 8;
            Bt[(size_t)n2 * 1024 + kb + tx] = f2bf(tile[tx][ty + i * 8]);
        }
    } else {
        int idx = (bid - 6144) * 256 + tid;  // < 15360
        int w = idx >> 10, j = idx & 1023;
        float acc = b1[j];
#pragma unroll
        for (int c = 0; c < 64; ++c)
            acc = fmaf(wemb[w * 64 + c], W1[(size_t)(2048 + c) * 1024 + j], acc);
        Rbf[idx] = f2bf(acc);
    }
}

// ---- 2. bf16 MFMA GEMM, BK=64 (two [128][32] LDS sub-tiles), XCD swizzle ----
__global__ __launch_bounds__(256) void k_gemm(const ushort* __restrict__ A,
                                              const ushort* __restrict__ Bt,
                                              ushort* __restrict__ P,
                                              ushort* __restrict__ Q) {
    __shared__ ushort Al[2 * 128 * 32];
    __shared__ ushort Bl[2 * 128 * 32];
    const int tid = threadIdx.x;
    const int wid = tid >> 6;
    const int lane = tid & 63;
    // XCD-aware bijective swizzle: 512 blocks, 8 XCDs, 64 per XCD
    const int bid = blockIdx.x;
    const int swz = ((bid & 7) << 6) | (bid >> 3);
    const int n0 = (swz & 15) * 128;
    const int m0 = (swz >> 4) * 128;
    const int wm = (wid >> 1) * 64;
    const int wn = (wid & 1) * 64;
    const int srow = lane >> 2;        // 0..15 within 16-row chunk
    const int scol = (lane & 3) * 8;   // element col within 32-col half
    const int fr = lane & 15;
    const int fk = (lane >> 4) * 8;

    f32x4 acc[4][4] = {};

    for (int k0 = 0; k0 < 1024; k0 += 64) {
#pragma unroll
        for (int r = 0; r < 4; ++r) {
            int c = wid + 4 * r;            // chunk 0..15
            int half = c >> 3;              // K-half (0: k0+0..31, 1: k0+32..63)
            int rows = (c & 7) * 16;        // 16-row group
            const ushort* sa = A  + (size_t)(m0 + rows + srow) * 1024 + k0 + half * 32 + scol;
            const ushort* sb = Bt + (size_t)(n0 + rows + srow) * 1024 + k0 + half * 32 + scol;
            int loff = half * 4096 + rows * 32;
            __builtin_amdgcn_global_load_lds((const __attribute__((address_space(1))) void*)sa,
                                             (__attribute__((address_space(3))) void*)(Al + loff),
                                             16, 0, 0);
            __builtin_amdgcn_global_load_lds((const __attribute__((address_space(1))) void*)sb,
                                             (__attribute__((address_space(3))) void*)(Bl + loff),
                                             16, 0, 0);
        }
        __syncthreads();
#pragma unroll
        for (int kk = 0; kk < 2; ++kk) {
            bf16x8 af[4], bg[4];
#pragma unroll
            for (int i = 0; i < 4; ++i) {
                af[i] = *(const bf16x8*)(Al + kk * 4096 + (wm + i * 16 + fr) * 32 + fk);
                bg[i] = *(const bf16x8*)(Bl + kk * 4096 + (wn + i * 16 + fr) * 32 + fk);
            }
#pragma unroll
            for (int i = 0; i < 4; ++i)
#pragma unroll
                for (int j = 0; j < 4; ++j)
                    acc[i][j] = __builtin_amdgcn_mfma_f32_16x16x32_bf16(af[i], bg[j], acc[i][j], 0, 0, 0);
        }
        __syncthreads();
    }

    ushort* Cb = (n0 < 1024) ? P : Q;
    const int nc0 = n0 & 1023;
    const int cr = (lane >> 4) * 4;
    const int cc = lane & 15;
#pragma unroll
    for (int i = 0; i < 4; ++i)
#pragma unroll
        for (int j = 0; j < 4; ++j) {
            ushort* Cp = Cb + (size_t)(m0 + wm + i * 16 + cr) * 1024 + (nc0 + wn + j * 16 + cc);
#pragma unroll
            for (int r = 0; r < 4; ++r)
                Cp[(size_t)r * 1024] = f2bf(acc[i][j][r]);
        }
}

// ---- 3. span pass with reuse tiling ----
__global__ __launch_bounds__(1024) void k_span2(const ushort* __restrict__ Pmat,
                                                const ushort* __restrict__ Qmat,
                                                const ushort* __restrict__ Rbf,
                                                const float* __restrict__ W2,
                                                const float* __restrict__ b2,
                                                float* __restrict__ out, int nspans) {
    __shared__ ushort Qs[30 * 1024];
    __shared__ ushort Rs[15 * 1024];
    const int tid = threadIdx.x;
    const int wid = tid >> 6, lane = tid & 63;
    const int b = blockIdx.x >> 5;
    const int s0 = (blockIdx.x & 31) << 4;

#pragma unroll
    for (int i = 0; i < 4; ++i) {
        int c = wid + (i << 4);
        if (c < 60) {
            int g = (c << 9) + lane * 8;
            int row = s0 + (g >> 10);
            if (row > SEQ - 1) row = SEQ - 1;
            const ushort* src = Qmat + (((size_t)(b << 9) + row) << 10) + (g & 1023);
            __builtin_amdgcn_global_load_lds((const __attribute__((address_space(1))) void*)src,
                                             (__attribute__((address_space(3))) void*)(Qs + (c << 9)),
                                             16, 0, 0);
        }
    }
#pragma unroll
    for (int i = 0; i < 2; ++i) {
        int c = wid + (i << 4);
        if (c < 30) {
            int g = (c << 9) + lane * 8;
            __builtin_amdgcn_global_load_lds((const __attribute__((address_space(1))) void*)(Rbf + g),
                                             (__attribute__((address_space(3))) void*)(Rs + (c << 9)),
                                             16, 0, 0);
        }
    }

    float w2r[3][2][8];
#pragma unroll
    for (int it = 0; it < 2; ++it)
#pragma unroll
        for (int u = 0; u < 8; ++u) {
            int j = lane * 8 + it * 512 + u;
            w2r[0][it][u] = W2[j * 3 + 0];
            w2r[1][it][u] = W2[j * 3 + 1];
            w2r[2][it][u] = W2[j * 3 + 2];
        }
    const float bb0 = b2[0], bb1 = b2[1], bb2 = b2[2];

    const int s = s0 + wid;
    float pf[16];
    {
        const uint4* pr = (const uint4*)(Pmat + (((size_t)(b << 9) + s) << 10) + lane * 8);
        unpack8(pr[0], pf);
        unpack8(pr[64], pf + 8);
    }

    __syncthreads();

    const int rrem = SEQ - s;
    const int nsp = (rrem < 15) ? rrem : 15;
    const int off = (rrem >= 15) ? 15 * s : (7575 - (rrem * (rrem + 1)) / 2);
    float* op = out + ((size_t)b * nspans + off) * 3;

    for (int w = 0; w < nsp; ++w) {
        const int erow = wid + w;
        float a0 = 0.f, a1 = 0.f, a2 = 0.f;
#pragma unroll
        for (int it = 0; it < 2; ++it) {
            uint4 qv = *(const uint4*)((const char*)Qs + erow * 2048 + it * 1024 + lane * 16);
            uint4 rv = *(const uint4*)((const char*)Rs + w * 2048 + it * 1024 + lane * 16);
            float qf[8], rf[8];
            unpack8(qv, qf);
            unpack8(rv, rf);
#pragma unroll
            for (int u = 0; u < 8; ++u) {
                float h = pf[it * 8 + u] + qf[u] + rf[u];
                h = fmaxf(h, 0.f);
                a0 = fmaf(h, w2r[0][it][u], a0);
                a1 = fmaf(h, w2r[1][it][u], a1);
                a2 = fmaf(h, w2r[2][it][u], a2);
            }
        }
#pragma unroll
        for (int o = 32; o; o >>= 1) {
            a0 += __shfl_xor(a0, o);
            a1 += __shfl_xor(a1, o);
            a2 += __shfl_xor(a2, o);
        }
        if (lane == 0) {
            op[w * 3 + 0] = a0 + bb0;
            op[w * 3 + 1] = a1 + bb1;
            op[w * 3 + 2] = a2 + bb2;
        }
    }
}

extern "C" void kernel_launch(void* const* d_in, const int* in_sizes, int n_in,
                              void* d_out, int out_size, void* d_ws, size_t ws_size,
                              hipStream_t stream) {
    const float* seq    = (const float*)d_in[0];
    const float* wemb   = (const float*)d_in[1];
    const float* W1     = (const float*)d_in[2];
    const float* b1     = (const float*)d_in[3];
    const float* W2     = (const float*)d_in[4];
    const float* b2     = (const float*)d_in[5];
    float* out = (float*)d_out;
    int nspans = in_sizes[6];

    char* ws = (char*)d_ws;
    ushort* seqb = (ushort*)ws;                  // 8 MiB  (4096x1024 bf16)
    ushort* Bt   = (ushort*)(ws + (8u << 20));   // 4 MiB  (2048x1024 bf16)
    ushort* Pmat = (ushort*)(ws + (12u << 20));  // 8 MiB
    ushort* Qmat = (ushort*)(ws + (20u << 20));  // 8 MiB
    ushort* Rbf  = (ushort*)(ws + (28u << 20));  // 30 KiB

    hipLaunchKernelGGL(k_prep, dim3(6204), dim3(256), 0, stream,
                       seq, wemb, W1, b1, seqb, Bt, Rbf);
    hipLaunchKernelGGL(k_gemm, dim3(512), dim3(256), 0, stream, seqb, Bt, Pmat, Qmat);
    hipLaunchKernelGGL(k_span2, dim3(BATCH * (SEQ / 16)), dim3(1024), 0, stream,
                       Pmat, Qmat, Rbf, W2, b2, out, nspans);
}

// Round 5
// 59.145 us; speedup vs baseline: 2.0130x; 1.0599x over previous
//
#include <hip/hip_runtime.h>
#include <stdint.h>

#define SEQ 512
#define BATCH 8
#define HID 1024

typedef __attribute__((ext_vector_type(8))) __bf16 bf16x8;
typedef __attribute__((ext_vector_type(4))) float f32x4;

__device__ __forceinline__ unsigned short f2bf(float f) {
    unsigned int u = __float_as_uint(f);
    unsigned int r = 0x7fffu + ((u >> 16) & 1u);
    return (unsigned short)((u + r) >> 16);
}

__device__ __forceinline__ void unpack8(uint4 v, float* f) {
    f[0] = __uint_as_float(v.x << 16);
    f[1] = __uint_as_float(v.x & 0xffff0000u);
    f[2] = __uint_as_float(v.y << 16);
    f[3] = __uint_as_float(v.y & 0xffff0000u);
    f[4] = __uint_as_float(v.z << 16);
    f[5] = __uint_as_float(v.z & 0xffff0000u);
    f[6] = __uint_as_float(v.w << 16);
    f[7] = __uint_as_float(v.w & 0xffff0000u);
}

// ---- 1. merged prep ----
// blocks [0,4096): cast seq->bf16 (1,048,576 float4s)
// blocks [4096,6144): transpose W1[:2048] -> Bt bf16
// blocks [6144,6204): width table Rbf
__global__ __launch_bounds__(256) void k_prep(const float* __restrict__ seq,
                                              const float* __restrict__ wemb,
                                              const float* __restrict__ W1,
                                              const float* __restrict__ b1,
                                              ushort* __restrict__ seqb,
                                              ushort* __restrict__ Bt,
                                              ushort* __restrict__ Rbf) {
    __shared__ float tile[32][33];
    const int bid = blockIdx.x;
    const int tid = threadIdx.x;
    if (bid < 4096) {
        int i = bid * 256 + tid;  // < 1048576 = n4
        float4 v = ((const float4*)seq)[i];
        ushort4 o;
        o.x = f2bf(v.x); o.y = f2bf(v.y); o.z = f2bf(v.z); o.w = f2bf(v.w);
        ((ushort4*)seqb)[i] = o;
    } else if (bid < 6144) {
        int idx = bid - 4096;
        int nb = (idx & 63) * 32, kb = (idx >> 6) * 32;
        int tx = tid & 31, ty = tid >> 5;
        int n = nb + tx;
        int rb = (n < 1024) ? 0 : 1024;
        int nc = n - rb;
#pragma unroll
        for (int i = 0; i < 4; ++i) {
            int k = kb + ty + i * 8;
            tile[ty + i * 8][tx] = W1[(size_t)(rb + k) * 1024 + nc];
        }
        __syncthreads();
#pragma unroll
        for (int i = 0; i < 4; ++i) {
            int n2 = nb + ty + i * 8;
            Bt[(size_t)n2 * 1024 + kb + tx] = f2bf(tile[tx][ty + i * 8]);
        }
    } else {
        int idx = (bid - 6144) * 256 + tid;  // < 15360
        int w = idx >> 10, j = idx & 1023;
        float acc = b1[j];
#pragma unroll
        for (int c = 0; c < 64; ++c)
            acc = fmaf(wemb[w * 64 + c], W1[(size_t)(2048 + c) * 1024 + j], acc);
        Rbf[idx] = f2bf(acc);
    }
}

// ---- 2. bf16 MFMA GEMM: 128x128 tile, 8 waves (2Mx4N of 64x32), BK=64,
//         double-buffered LDS (2-phase pipeline), XCD swizzle ----
__global__ __launch_bounds__(512) void k_gemm(const ushort* __restrict__ A,
                                              const ushort* __restrict__ Bt,
                                              ushort* __restrict__ P,
                                              ushort* __restrict__ Q) {
    __shared__ ushort Al[2][8192];  // [buf][half*4096 + rows*32 + ...]
    __shared__ ushort Bl[2][8192];
    const int tid = threadIdx.x;
    const int wid = tid >> 6;     // 0..7
    const int lane = tid & 63;
    // XCD-aware bijective swizzle: 512 blocks, 8 XCDs, 64 per XCD
    const int bid = blockIdx.x;
    const int swz = ((bid & 7) << 6) | (bid >> 3);
    const int n0 = (swz & 15) * 128;
    const int m0 = (swz >> 4) * 128;
    const int wm = (wid >> 2) * 64;   // wave M offset (2 rows of waves)
    const int wn = (wid & 3) * 32;    // wave N offset (4 cols of waves)
    const int srow = lane >> 2;       // staging row within 16-row chunk
    const int scol = (lane & 3) * 8;  // staging col within 32-col half
    const int fr = lane & 15;
    const int fk = (lane >> 4) * 8;

    f32x4 acc[4][2] = {};

    const ushort* Abase = A  + (size_t)(m0 + srow) * 1024 + scol;
    const ushort* Bbase = Bt + (size_t)(n0 + srow) * 1024 + scol;

    // stage one BK=64 tile-pair into buffer `buf`: chunks c = wid, wid+8
#define STAGE(buf, k0)                                                                     \
    {                                                                                      \
        _Pragma("unroll")                                                                  \
        for (int r = 0; r < 2; ++r) {                                                      \
            int c = wid + 8 * r;                                                           \
            int half = c >> 3;                                                             \
            int rows = (c & 7) * 16;                                                       \
            const ushort* sa = Abase + (size_t)rows * 1024 + (k0) + half * 32;             \
            const ushort* sb = Bbase + (size_t)rows * 1024 + (k0) + half * 32;             \
            int loff = half * 4096 + rows * 32;                                            \
            __builtin_amdgcn_global_load_lds((const __attribute__((address_space(1))) void*)sa, \
                                             (__attribute__((address_space(3))) void*)(&Al[buf][loff]), \
                                             16, 0, 0);                                    \
            __builtin_amdgcn_global_load_lds((const __attribute__((address_space(1))) void*)sb, \
                                             (__attribute__((address_space(3))) void*)(&Bl[buf][loff]), \
                                             16, 0, 0);                                    \
        }                                                                                  \
    }

    STAGE(0, 0);
    __syncthreads();  // prologue: tile 0 resident

    for (int t = 0; t < 16; ++t) {
        const int cur = t & 1;
        if (t < 15) STAGE(cur ^ 1, (t + 1) * 64);  // prefetch next tile (async)
#pragma unroll
        for (int kk = 0; kk < 2; ++kk) {
            bf16x8 af[4], bg[2];
#pragma unroll
            for (int i = 0; i < 4; ++i)
                af[i] = *(const bf16x8*)(&Al[cur][kk * 4096 + (wm + i * 16 + fr) * 32 + fk]);
#pragma unroll
            for (int j = 0; j < 2; ++j)
                bg[j] = *(const bf16x8*)(&Bl[cur][kk * 4096 + (wn + j * 16 + fr) * 32 + fk]);
#pragma unroll
            for (int i = 0; i < 4; ++i)
#pragma unroll
                for (int j = 0; j < 2; ++j)
                    acc[i][j] = __builtin_amdgcn_mfma_f32_16x16x32_bf16(af[i], bg[j], acc[i][j], 0, 0, 0);
        }
        __syncthreads();  // drains prefetch (vmcnt) + protects buffer swap
    }
#undef STAGE

    ushort* Cb = (n0 < 1024) ? P : Q;
    const int nc0 = n0 & 1023;
    const int cr = (lane >> 4) * 4;
    const int cc = lane & 15;
#pragma unroll
    for (int i = 0; i < 4; ++i)
#pragma unroll
        for (int j = 0; j < 2; ++j) {
            ushort* Cp = Cb + (size_t)(m0 + wm + i * 16 + cr) * 1024 + (nc0 + wn + j * 16 + cc);
#pragma unroll
            for (int r = 0; r < 4; ++r)
                Cp[(size_t)r * 1024] = f2bf(acc[i][j][r]);
        }
}

// ---- 3. span pass with reuse tiling ----
__global__ __launch_bounds__(1024) void k_span2(const ushort* __restrict__ Pmat,
                                                const ushort* __restrict__ Qmat,
                                                const ushort* __restrict__ Rbf,
                                                const float* __restrict__ W2,
                                                const float* __restrict__ b2,
                                                float* __restrict__ out, int nspans) {
    __shared__ ushort Qs[30 * 1024];
    __shared__ ushort Rs[15 * 1024];
    const int tid = threadIdx.x;
    const int wid = tid >> 6, lane = tid & 63;
    const int b = blockIdx.x >> 5;
    const int s0 = (blockIdx.x & 31) << 4;

#pragma unroll
    for (int i = 0; i < 4; ++i) {
        int c = wid + (i << 4);
        if (c < 60) {
            int g = (c << 9) + lane * 8;
            int row = s0 + (g >> 10);
            if (row > SEQ - 1) row = SEQ - 1;
            const ushort* src = Qmat + (((size_t)(b << 9) + row) << 10) + (g & 1023);
            __builtin_amdgcn_global_load_lds((const __attribute__((address_space(1))) void*)src,
                                             (__attribute__((address_space(3))) void*)(Qs + (c << 9)),
                                             16, 0, 0);
        }
    }
#pragma unroll
    for (int i = 0; i < 2; ++i) {
        int c = wid + (i << 4);
        if (c < 30) {
            int g = (c << 9) + lane * 8;
            __builtin_amdgcn_global_load_lds((const __attribute__((address_space(1))) void*)(Rbf + g),
                                             (__attribute__((address_space(3))) void*)(Rs + (c << 9)),
                                             16, 0, 0);
        }
    }

    float w2r[3][2][8];
#pragma unroll
    for (int it = 0; it < 2; ++it)
#pragma unroll
        for (int u = 0; u < 8; ++u) {
            int j = lane * 8 + it * 512 + u;
            w2r[0][it][u] = W2[j * 3 + 0];
            w2r[1][it][u] = W2[j * 3 + 1];
            w2r[2][it][u] = W2[j * 3 + 2];
        }
    const float bb0 = b2[0], bb1 = b2[1], bb2 = b2[2];

    const int s = s0 + wid;
    float pf[16];
    {
        const uint4* pr = (const uint4*)(Pmat + (((size_t)(b << 9) + s) << 10) + lane * 8);
        unpack8(pr[0], pf);
        unpack8(pr[64], pf + 8);
    }

    __syncthreads();

    const int rrem = SEQ - s;
    const int nsp = (rrem < 15) ? rrem : 15;
    const int off = (rrem >= 15) ? 15 * s : (7575 - (rrem * (rrem + 1)) / 2);
    float* op = out + ((size_t)b * nspans + off) * 3;

    for (int w = 0; w < nsp; ++w) {
        const int erow = wid + w;
        float a0 = 0.f, a1 = 0.f, a2 = 0.f;
#pragma unroll
        for (int it = 0; it < 2; ++it) {
            uint4 qv = *(const uint4*)((const char*)Qs + erow * 2048 + it * 1024 + lane * 16);
            uint4 rv = *(const uint4*)((const char*)Rs + w * 2048 + it * 1024 + lane * 16);
            float qf[8], rf[8];
            unpack8(qv, qf);
            unpack8(rv, rf);
#pragma unroll
            for (int u = 0; u < 8; ++u) {
                float h = pf[it * 8 + u] + qf[u] + rf[u];
                h = fmaxf(h, 0.f);
                a0 = fmaf(h, w2r[0][it][u], a0);
                a1 = fmaf(h, w2r[1][it][u], a1);
                a2 = fmaf(h, w2r[2][it][u], a2);
            }
        }
#pragma unroll
        for (int o = 32; o; o >>= 1) {
            a0 += __shfl_xor(a0, o);
            a1 += __shfl_xor(a1, o);
            a2 += __shfl_xor(a2, o);
        }
        if (lane == 0) {
            op[w * 3 + 0] = a0 + bb0;
            op[w * 3 + 1] = a1 + bb1;
            op[w * 3 + 2] = a2 + bb2;
        }
    }
}

extern "C" void kernel_launch(void* const* d_in, const int* in_sizes, int n_in,
                              void* d_out, int out_size, void* d_ws, size_t ws_size,
                              hipStream_t stream) {
    const float* seq    = (const float*)d_in[0];
    const float* wemb   = (const float*)d_in[1];
    const float* W1     = (const float*)d_in[2];
    const float* b1     = (const float*)d_in[3];
    const float* W2     = (const float*)d_in[4];
    const float* b2     = (const float*)d_in[5];
    float* out = (float*)d_out;
    int nspans = in_sizes[6];

    char* ws = (char*)d_ws;
    ushort* seqb = (ushort*)ws;                  // 8 MiB  (4096x1024 bf16)
    ushort* Bt   = (ushort*)(ws + (8u << 20));   // 4 MiB  (2048x1024 bf16)
    ushort* Pmat = (ushort*)(ws + (12u << 20));  // 8 MiB
    ushort* Qmat = (ushort*)(ws + (20u << 20));  // 8 MiB
    ushort* Rbf  = (ushort*)(ws + (28u << 20));  // 30 KiB

    hipLaunchKernelGGL(k_prep, dim3(6204), dim3(256), 0, stream,
                       seq, wemb, W1, b1, seqb, Bt, Rbf);
    hipLaunchKernelGGL(k_gemm, dim3(512), dim3(512), 0, stream, seqb, Bt, Pmat, Qmat);
    hipLaunchKernelGGL(k_span2, dim3(BATCH * (SEQ / 16)), dim3(1024), 0, stream,
                       Pmat, Qmat, Rbf, W2, b2, out, nspans);
}